// Round 6
// baseline (181.885 us; speedup 1.0000x reference)
//
#include <hip/hip_runtime.h>

#define H_IMG 128
#define W_IMG 128
#define NQ (H_IMG * W_IMG)
#define CIN 256
#define NH 8
#define NP 4
#define DH 32
#define LDSP 264  // padded LDS row stride (bf16 elems); 2-way max bank aliasing (free)

typedef __bf16 bf16x4 __attribute__((ext_vector_type(4)));
typedef __bf16 bf16x8 __attribute__((ext_vector_type(8)));
typedef float f32x4 __attribute__((ext_vector_type(4)));

// ---------------- weight prep: transpose to BT[N][K] and cast to bf16 ----------------
__global__ __launch_bounds__(256) void prep_weights(
    const float* __restrict__ Wval, const float* __restrict__ Wout,
    const float* __restrict__ Woff, const float* __restrict__ Wattn,
    const float* __restrict__ boff, const float* __restrict__ battn,
    __bf16* __restrict__ btv, __bf16* __restrict__ bto,
    __bf16* __restrict__ btoa, float* __restrict__ bias96) {
  int id = blockIdx.x * 256 + threadIdx.x;
  if (id < 256 * 256) {
    int n = id >> 8, k = id & 255;
    btv[n * 256 + k] = (__bf16)Wval[k * 256 + n];
    bto[n * 256 + k] = (__bf16)Wout[k * 256 + n];
  }
  if (id < 96 * 256) {
    int n = id >> 8, k = id & 255;
    float w = (n < 64) ? Woff[k * 64 + n] : Wattn[k * 32 + (n - 64)];
    btoa[n * 256 + k] = (__bf16)w;
  }
  if (id < 96) {
    bias96[id] = (id < 64) ? boff[id] : battn[id - 64];
  }
}

// ---------------- K1: v = value @ W_val + b_val (head-planar bf16 out) -------------
// BM=32 x full N=256 per block (A read exactly once); 1024 blocks -> ~4+ blocks/CU
// so staging/compute of different blocks overlap on each CU. Wave w covers all 32
// rows (2 m-tiles) x cols [w*64, w*64+64) (4 n-tiles) = 8 accs, 64 MFMA/wave.
// B-frags streamed from global btv (128 KB, L2-hot).
// mfma_f32_16x16x32_bf16 layouts (HW-verified, carried from passing rounds):
//   A frag: lane holds A[m = lane&15][k = (lane>>4)*8 + j]
//   B frag: lane holds BT[n = lane&15][k = (lane>>4)*8 + j]
//   C/D:    col = lane&15, row = (lane>>4)*4 + reg
__global__ __launch_bounds__(256) void gemm_v(
    const float* __restrict__ A, const __bf16* __restrict__ BT,
    const float* __restrict__ bias, __bf16* __restrict__ v, int M) {
  const int t = threadIdx.x;
  const int lane = t & 63;
  const int wave = t >> 6;
  const int r = lane & 15;
  const int q = lane >> 4;
  const int gm0 = blockIdx.x * 32;
  const int wn = wave * 64;

  __shared__ __bf16 As[32 * LDSP];

  // stage A (32 x 256 fp32 -> bf16), coalesced
#pragma unroll
  for (int i = 0; i < 8; ++i) {
    int g = i * 256 + t;
    int row = g >> 6, c4 = g & 63;
    float4 f = *(const float4*)(A + (size_t)(gm0 + row) * 256 + c4 * 4);
    bf16x4 hh;
    hh[0] = (__bf16)f.x; hh[1] = (__bf16)f.y;
    hh[2] = (__bf16)f.z; hh[3] = (__bf16)f.w;
    *(bf16x4*)(&As[row * LDSP + c4 * 4]) = hh;
  }
  __syncthreads();

  f32x4 acc[2][4];
#pragma unroll
  for (int mt = 0; mt < 2; ++mt)
#pragma unroll
    for (int nt = 0; nt < 4; ++nt) acc[mt][nt] = (f32x4){0.f, 0.f, 0.f, 0.f};

#pragma unroll
  for (int kt = 0; kt < 8; ++kt) {
    const int ko = kt * 32 + q * 8;
    bf16x8 a[2], b[4];
#pragma unroll
    for (int mt = 0; mt < 2; ++mt)
      a[mt] = *(const bf16x8*)(&As[(mt * 16 + r) * LDSP + ko]);
#pragma unroll
    for (int nt = 0; nt < 4; ++nt)
      b[nt] = *(const bf16x8*)(BT + (size_t)(wn + nt * 16 + r) * 256 + ko);
#pragma unroll
    for (int mt = 0; mt < 2; ++mt)
#pragma unroll
      for (int nt = 0; nt < 4; ++nt)
        acc[mt][nt] =
            __builtin_amdgcn_mfma_f32_16x16x32_bf16(a[mt], b[nt], acc[mt][nt], 0, 0, 0);
  }

  // epilogue: head-planar scatter v[head][row][col&31]
#pragma unroll
  for (int mt = 0; mt < 2; ++mt)
#pragma unroll
    for (int nt = 0; nt < 4; ++nt)
#pragma unroll
      for (int rr = 0; rr < 4; ++rr) {
        int row = gm0 + mt * 16 + q * 4 + rr;
        int col = wn + nt * 16 + r;
        v[((size_t)(col >> 5) * M + row) * 32 + (col & 31)] =
            (__bf16)(acc[mt][nt][rr] + bias[col]);
      }
}

// ---------------- K2: oa GEMM + sampling + output GEMM, fully fused ----------------
// BM=32 queries/block, 1024 blocks, ~30 KB LDS -> 4-5 blocks/CU so the barrier-
// separated phases of DIFFERENT blocks overlap on each CU (gather latency hides
// under another block's MFMA). Phases:
//  1. stage query tile -> bf16 As (one barrier)
//  2. oa[32x96] = q @ btoa^T + bias96 -> oas LDS  (waves: 1m x 3n)
//  3. softmax + bilinear sampling from head-planar v -> attn tile into As
//     (8 threads/query: 2 head-parities x 4 d-chunks; 4 heads per thread)
//  4. out = attn(LDS) @ bto^T + b_out + query -> global (waves: 2m x 4n)
__global__ __launch_bounds__(256) void oa_sample_out(
    const float* __restrict__ query, const __bf16* __restrict__ btoa,
    const float* __restrict__ bias96, const __bf16* __restrict__ v,
    const __bf16* __restrict__ bto, const float* __restrict__ b_out,
    float* __restrict__ out, int M) {
  const int t = threadIdx.x;
  const int lane = t & 63;
  const int wave = t >> 6;
  const int r = lane & 15;
  const int q = lane >> 4;
  const int gm0 = blockIdx.x * 32;

  __shared__ __bf16 As[32 * LDSP];
  __shared__ float oas[32 * 100];

  // ---- phase 1: stage query (32 x 256 fp32 -> bf16) ----
#pragma unroll
  for (int i = 0; i < 8; ++i) {
    int g = i * 256 + t;
    int row = g >> 6, c4 = g & 63;
    float4 f = *(const float4*)(query + (size_t)(gm0 + row) * 256 + c4 * 4);
    bf16x4 hh;
    hh[0] = (__bf16)f.x; hh[1] = (__bf16)f.y;
    hh[2] = (__bf16)f.z; hh[3] = (__bf16)f.w;
    *(bf16x4*)(&As[row * LDSP + c4 * 4]) = hh;
  }
  __syncthreads();

  // ---- phase 2: oa GEMM (wave: 1 m-tile (wave&1) x 3 n-tiles (wave>>1)) ----
  {
    const int wm = (wave & 1) * 16;
    const int n0 = (wave >> 1) * 48;
    f32x4 acc[3];
#pragma unroll
    for (int nt = 0; nt < 3; ++nt) acc[nt] = (f32x4){0.f, 0.f, 0.f, 0.f};
#pragma unroll
    for (int kt = 0; kt < 8; ++kt) {
      const int ko = kt * 32 + q * 8;
      bf16x8 a0 = *(const bf16x8*)(&As[(wm + r) * LDSP + ko]);
      bf16x8 b[3];
#pragma unroll
      for (int nt = 0; nt < 3; ++nt)
        b[nt] = *(const bf16x8*)(btoa + (size_t)(n0 + nt * 16 + r) * 256 + ko);
#pragma unroll
      for (int nt = 0; nt < 3; ++nt)
        acc[nt] = __builtin_amdgcn_mfma_f32_16x16x32_bf16(a0, b[nt], acc[nt], 0, 0, 0);
    }
#pragma unroll
    for (int nt = 0; nt < 3; ++nt)
#pragma unroll
      for (int rr = 0; rr < 4; ++rr) {
        int rl = wm + q * 4 + rr;
        int col = (wave >> 1) * 48 + nt * 16 + r;
        oas[rl * 100 + col] = acc[nt][rr] + bias96[col];
      }
  }
  __syncthreads();  // oas ready; all As reads drained -> As reusable for attn

  // ---- phase 3: sample 32 queries, write attn tile into As ----
  {
    const int qrow = t >> 3;         // 0..31
    const int hh = (t >> 2) & 1;     // head parity
    const int c8 = (t & 3) * 8;      // d-chunk (8 bf16 = 16 B)
    const int row = gm0 + qrow;
    const int b = row >> 14;  // nq = 16384
    const int qi = row & (NQ - 1);
    const int x = qi & (W_IMG - 1);
    const int y = qi >> 7;
    const float* oar = &oas[qrow * 100];
#pragma unroll
    for (int i = 0; i < 4; ++i) {
      const int h = hh + 2 * i;
      float l0 = oar[64 + h * 4 + 0];
      float l1 = oar[64 + h * 4 + 1];
      float l2 = oar[64 + h * 4 + 2];
      float l3 = oar[64 + h * 4 + 3];
      float mx = fmaxf(fmaxf(l0, l1), fmaxf(l2, l3));
      float e0 = __expf(l0 - mx), e1 = __expf(l1 - mx);
      float e2 = __expf(l2 - mx), e3 = __expf(l3 - mx);
      float inv = 1.f / (e0 + e1 + e2 + e3);
      float awp[4] = {e0 * inv, e1 * inv, e2 * inv, e3 * inv};
      float fa[8] = {0.f, 0.f, 0.f, 0.f, 0.f, 0.f, 0.f, 0.f};
      const __bf16* vh = v + ((size_t)h * M + (size_t)b * NQ) * 32 + c8;
#pragma unroll
      for (int p = 0; p < NP; ++p) {
        float ox = oar[h * 8 + p * 2 + 0];
        float oy = oar[h * 8 + p * 2 + 1];
        float ix = (float)x + ox;
        float iy = (float)y + oy;
        float x0f = floorf(ix), y0f = floorf(iy);
        float wx1 = ix - x0f, wy1 = iy - y0f;
        int x0 = (int)x0f, y0 = (int)y0f;
        float wgt[4] = {(1.f - wx1) * (1.f - wy1), wx1 * (1.f - wy1),
                        (1.f - wx1) * wy1, wx1 * wy1};
        int xs[4] = {x0, x0 + 1, x0, x0 + 1};
        int ysv[4] = {y0, y0, y0 + 1, y0 + 1};
#pragma unroll
        for (int c = 0; c < 4; ++c) {
          int xi = xs[c], yi = ysv[c];
          bool valid = (xi >= 0) & (xi < W_IMG) & (yi >= 0) & (yi < H_IMG);
          int xc = xi < 0 ? 0 : (xi > W_IMG - 1 ? W_IMG - 1 : xi);
          int yc = yi < 0 ? 0 : (yi > H_IMG - 1 ? H_IMG - 1 : yi);
          float wv = awp[p] * wgt[c] * (valid ? 1.f : 0.f);
          bf16x8 g = *(const bf16x8*)(vh + (size_t)(yc * W_IMG + xc) * 32);
#pragma unroll
          for (int j = 0; j < 8; ++j) fa[j] += wv * (float)g[j];
        }
      }
      bf16x8 o;
#pragma unroll
      for (int j = 0; j < 8; ++j) o[j] = (__bf16)fa[j];
      *(bf16x8*)(&As[qrow * LDSP + h * DH + c8]) = o;
    }
  }
  __syncthreads();  // attn tile ready in As

  // ---- phase 4: out GEMM (wave: 32 rows (2 m-tiles) x 64 cols (4 n-tiles)) ----
  {
    const int wn = wave * 64;
    f32x4 acc[2][4];
#pragma unroll
    for (int mt = 0; mt < 2; ++mt)
#pragma unroll
      for (int nt = 0; nt < 4; ++nt) acc[mt][nt] = (f32x4){0.f, 0.f, 0.f, 0.f};
#pragma unroll
    for (int kt = 0; kt < 8; ++kt) {
      const int ko = kt * 32 + q * 8;
      bf16x8 a[2], b[4];
#pragma unroll
      for (int mt = 0; mt < 2; ++mt)
        a[mt] = *(const bf16x8*)(&As[(mt * 16 + r) * LDSP + ko]);
#pragma unroll
      for (int nt = 0; nt < 4; ++nt)
        b[nt] = *(const bf16x8*)(bto + (size_t)(wn + nt * 16 + r) * 256 + ko);
#pragma unroll
      for (int mt = 0; mt < 2; ++mt)
#pragma unroll
        for (int nt = 0; nt < 4; ++nt)
          acc[mt][nt] =
              __builtin_amdgcn_mfma_f32_16x16x32_bf16(a[mt], b[nt], acc[mt][nt], 0, 0, 0);
    }
#pragma unroll
    for (int mt = 0; mt < 2; ++mt)
#pragma unroll
      for (int nt = 0; nt < 4; ++nt)
#pragma unroll
        for (int rr = 0; rr < 4; ++rr) {
          int row = gm0 + mt * 16 + q * 4 + rr;
          int col = wn + nt * 16 + r;
          out[(size_t)row * 256 + col] =
              acc[mt][nt][rr] + b_out[col] + query[(size_t)row * 256 + col];
        }
  }
}

extern "C" void kernel_launch(void* const* d_in, const int* in_sizes, int n_in,
                              void* d_out, int out_size, void* d_ws, size_t ws_size,
                              hipStream_t stream) {
  const float* query  = (const float*)d_in[0];
  const float* value  = (const float*)d_in[1];
  const float* W_off  = (const float*)d_in[2];
  const float* b_off  = (const float*)d_in[3];
  const float* W_attn = (const float*)d_in[4];
  const float* b_attn = (const float*)d_in[5];
  const float* W_val  = (const float*)d_in[6];
  const float* b_val  = (const float*)d_in[7];
  const float* W_out  = (const float*)d_in[8];
  const float* b_out  = (const float*)d_in[9];
  float* out = (float*)d_out;

  char* ws = (char*)d_ws;
  __bf16* btv    = (__bf16*)(ws + 0);          // 128 KB
  __bf16* bto    = (__bf16*)(ws + 131072);     // 128 KB
  __bf16* btoa   = (__bf16*)(ws + 262144);     // 48 KB
  float*  bias96 = (float*)(ws + 311296);      // 384 B
  __bf16* v      = (__bf16*)(ws + 524288);     // 16 MB (bf16, head-planar)

  const int M = in_sizes[0] / CIN;  // 32768 = bs * nq

  prep_weights<<<256, 256, 0, stream>>>(W_val, W_out, W_off, W_attn,
                                        b_off, b_attn, btv, bto, btoa, bias96);
  gemm_v<<<M / 32, 256, 0, stream>>>(value, btv, b_val, v, M);
  oa_sample_out<<<M / 32, 256, 0, stream>>>(query, btoa, bias96, v, bto, b_out, out, M);
}

// Round 7
// 171.323 us; speedup vs baseline: 1.0617x; 1.0617x over previous
//
#include <hip/hip_runtime.h>

#define H_IMG 128
#define W_IMG 128
#define NQ (H_IMG * W_IMG)
#define CIN 256
#define NH 8
#define NP 4
#define DH 32
#define LDSP 264  // padded LDS row stride (bf16 elems); 2-way max bank aliasing (free)

typedef __bf16 bf16x4 __attribute__((ext_vector_type(4)));
typedef __bf16 bf16x8 __attribute__((ext_vector_type(8)));
typedef float f32x4 __attribute__((ext_vector_type(4)));

// ---------------- weight prep: transpose to BT[N][K] and cast to bf16 ----------------
__global__ __launch_bounds__(256) void prep_weights(
    const float* __restrict__ Wval, const float* __restrict__ Wout,
    const float* __restrict__ Woff, const float* __restrict__ Wattn,
    const float* __restrict__ boff, const float* __restrict__ battn,
    __bf16* __restrict__ btv, __bf16* __restrict__ bto,
    __bf16* __restrict__ btoa, float* __restrict__ bias96) {
  int id = blockIdx.x * 256 + threadIdx.x;
  if (id < 256 * 256) {
    int n = id >> 8, k = id & 255;
    btv[n * 256 + k] = (__bf16)Wval[k * 256 + n];
    bto[n * 256 + k] = (__bf16)Wout[k * 256 + n];
  }
  if (id < 96 * 256) {
    int n = id >> 8, k = id & 255;
    float w = (n < 64) ? Woff[k * 64 + n] : Wattn[k * 32 + (n - 64)];
    btoa[n * 256 + k] = (__bf16)w;
  }
  if (id < 96) {
    bias96[id] = (id < 64) ? boff[id] : battn[id - 64];
  }
}

// XCD-contiguous block swizzle: with round-robin blockIdx->XCD dispatch, XCD k gets
// the contiguous block range [k*grid/8, (k+1)*grid/8) -> contiguous query span, so
// v's per-XCD working set (~3.8 MB incl. sampling margin) fits the 4 MB XCD L2.
__device__ __forceinline__ int swizzle_bx(int b, int grid) {
  return (b & 7) * (grid >> 3) + (b >> 3);
}

// ---------------- K1: v = value @ W_val + b_val (head-planar bf16 out) -------------
// BM=64 x full N=256 per block (A read exactly once). Wave w: all 64 rows (4 m-tiles)
// x cols [w*64, w*64+64) (4 n-tiles) = 16 accs, 128 MFMA. B-frags from L2-hot btv
// with next-k software prefetch (load k+1 overlaps MFMA of k).
// mfma_f32_16x16x32_bf16 layouts (HW-verified, carried from passing rounds):
//   A frag: lane holds A[m = lane&15][k = (lane>>4)*8 + j]
//   B frag: lane holds BT[n = lane&15][k = (lane>>4)*8 + j]
//   C/D:    col = lane&15, row = (lane>>4)*4 + reg
__global__ __launch_bounds__(256, 4) void gemm_v(
    const float* __restrict__ A, const __bf16* __restrict__ BT,
    const float* __restrict__ bias, __bf16* __restrict__ v, int M) {
  const int t = threadIdx.x;
  const int lane = t & 63;
  const int wave = t >> 6;
  const int r = lane & 15;
  const int q = lane >> 4;
  const int bx = swizzle_bx(blockIdx.x, gridDim.x);
  const int gm0 = bx * 64;
  const int wn = wave * 64;

  __shared__ __bf16 As[64 * LDSP];

  // stage A (64 x 256 fp32 -> bf16), coalesced
#pragma unroll
  for (int i = 0; i < 16; ++i) {
    int g = i * 256 + t;
    int row = g >> 6, c4 = g & 63;
    float4 f = *(const float4*)(A + (size_t)(gm0 + row) * 256 + c4 * 4);
    bf16x4 hh;
    hh[0] = (__bf16)f.x; hh[1] = (__bf16)f.y;
    hh[2] = (__bf16)f.z; hh[3] = (__bf16)f.w;
    *(bf16x4*)(&As[row * LDSP + c4 * 4]) = hh;
  }
  __syncthreads();

  f32x4 acc[4][4];
#pragma unroll
  for (int mt = 0; mt < 4; ++mt)
#pragma unroll
    for (int nt = 0; nt < 4; ++nt) acc[mt][nt] = (f32x4){0.f, 0.f, 0.f, 0.f};

  bf16x8 bnx[4];
#pragma unroll
  for (int nt = 0; nt < 4; ++nt)
    bnx[nt] = *(const bf16x8*)(BT + (size_t)(wn + nt * 16 + r) * 256 + q * 8);

#pragma unroll
  for (int kt = 0; kt < 8; ++kt) {
    const int ko = kt * 32 + q * 8;
    bf16x8 b[4];
#pragma unroll
    for (int nt = 0; nt < 4; ++nt) b[nt] = bnx[nt];
    if (kt < 7) {
#pragma unroll
      for (int nt = 0; nt < 4; ++nt)
        bnx[nt] = *(const bf16x8*)(BT + (size_t)(wn + nt * 16 + r) * 256 + ko + 32);
    }
    bf16x8 a[4];
#pragma unroll
    for (int mt = 0; mt < 4; ++mt)
      a[mt] = *(const bf16x8*)(&As[(mt * 16 + r) * LDSP + ko]);
#pragma unroll
    for (int mt = 0; mt < 4; ++mt)
#pragma unroll
      for (int nt = 0; nt < 4; ++nt)
        acc[mt][nt] =
            __builtin_amdgcn_mfma_f32_16x16x32_bf16(a[mt], b[nt], acc[mt][nt], 0, 0, 0);
  }

  // epilogue: head-planar scatter v[head][row][col&31]
#pragma unroll
  for (int mt = 0; mt < 4; ++mt)
#pragma unroll
    for (int nt = 0; nt < 4; ++nt)
#pragma unroll
      for (int rr = 0; rr < 4; ++rr) {
        int row = gm0 + mt * 16 + q * 4 + rr;
        int col = wn + nt * 16 + r;
        v[((size_t)(col >> 5) * M + row) * 32 + (col & 31)] =
            (__bf16)(acc[mt][nt][rr] + bias[col]);
      }
}

// ---------------- K2: oa GEMM + sampling + output GEMM, fully fused ----------------
// BM=64 queries/block (best measured: 47 vs 55 µs for BM=32). Phases (LDS reused):
//  1. stage query tile -> bf16 As (one barrier)
//  2. oa[64x96] = q @ btoa^T + bias96 -> oas LDS (waves 2m x 3n, next-k B prefetch)
//  3. softmax + bilinear sampling from head-planar v -> attn tile written into As
//  4. out = attn(LDS) @ bto^T + b_out + residual -> global. Residual fp32 loads are
//     ISSUED BEFORE the k-loop (64 VGPRs; free at 2 blocks/CU via launch_bounds(256,2))
//     so their HBM latency hides under the 128 MFMAs instead of stalling the epilogue.
__global__ __launch_bounds__(256, 2) void oa_sample_out(
    const float* __restrict__ query, const __bf16* __restrict__ btoa,
    const float* __restrict__ bias96, const __bf16* __restrict__ v,
    const __bf16* __restrict__ bto, const float* __restrict__ b_out,
    float* __restrict__ out, int M) {
  const int t = threadIdx.x;
  const int lane = t & 63;
  const int wave = t >> 6;
  const int r = lane & 15;
  const int q = lane >> 4;
  const int bx = swizzle_bx(blockIdx.x, gridDim.x);
  const int gm0 = bx * 64;

  __shared__ __bf16 As[64 * LDSP];
  __shared__ float oas[64 * 100];

  // ---- phase 1: stage query (64 x 256 fp32 -> bf16) ----
#pragma unroll
  for (int i = 0; i < 16; ++i) {
    int g = i * 256 + t;
    int row = g >> 6, c4 = g & 63;
    float4 f = *(const float4*)(query + (size_t)(gm0 + row) * 256 + c4 * 4);
    bf16x4 hh;
    hh[0] = (__bf16)f.x; hh[1] = (__bf16)f.y;
    hh[2] = (__bf16)f.z; hh[3] = (__bf16)f.w;
    *(bf16x4*)(&As[row * LDSP + c4 * 4]) = hh;
  }
  __syncthreads();

  // ---- phase 2: oa GEMM (wave: 2 m-tiles x 3 n-tiles, next-k B prefetch) ----
  {
    const int wm = (wave & 1) * 32;
    const int n0 = (wave >> 1) * 48;
    f32x4 acc[2][3];
#pragma unroll
    for (int mt = 0; mt < 2; ++mt)
#pragma unroll
      for (int nt = 0; nt < 3; ++nt) acc[mt][nt] = (f32x4){0.f, 0.f, 0.f, 0.f};
    bf16x8 bnx[3];
#pragma unroll
    for (int nt = 0; nt < 3; ++nt)
      bnx[nt] = *(const bf16x8*)(btoa + (size_t)(n0 + nt * 16 + r) * 256 + q * 8);
#pragma unroll
    for (int kt = 0; kt < 8; ++kt) {
      const int ko = kt * 32 + q * 8;
      bf16x8 b[3];
#pragma unroll
      for (int nt = 0; nt < 3; ++nt) b[nt] = bnx[nt];
      if (kt < 7) {
#pragma unroll
        for (int nt = 0; nt < 3; ++nt)
          bnx[nt] = *(const bf16x8*)(btoa + (size_t)(n0 + nt * 16 + r) * 256 + ko + 32);
      }
      bf16x8 a0 = *(const bf16x8*)(&As[(wm + r) * LDSP + ko]);
      bf16x8 a1 = *(const bf16x8*)(&As[(wm + 16 + r) * LDSP + ko]);
#pragma unroll
      for (int nt = 0; nt < 3; ++nt) {
        acc[0][nt] = __builtin_amdgcn_mfma_f32_16x16x32_bf16(a0, b[nt], acc[0][nt], 0, 0, 0);
        acc[1][nt] = __builtin_amdgcn_mfma_f32_16x16x32_bf16(a1, b[nt], acc[1][nt], 0, 0, 0);
      }
    }
#pragma unroll
    for (int mt = 0; mt < 2; ++mt)
#pragma unroll
      for (int nt = 0; nt < 3; ++nt)
#pragma unroll
        for (int rr = 0; rr < 4; ++rr) {
          int rl = wm + mt * 16 + q * 4 + rr;
          int col = n0 + nt * 16 + r;
          oas[rl * 100 + col] = acc[mt][nt][rr] + bias96[col];
        }
  }
  __syncthreads();  // oas ready; As reads drained -> As reusable for attn

  // ---- phase 3: sample 64 queries (4 threads/query x 8 heads), attn -> As ----
  {
    const int qrow = t >> 2;
    const int c8 = (t & 3) * 8;
    const int row = gm0 + qrow;
    const int b = row >> 14;  // nq = 16384
    const int qi = row & (NQ - 1);
    const int x = qi & (W_IMG - 1);
    const int y = qi >> 7;
    const float* oar = &oas[qrow * 100];
#pragma unroll
    for (int h = 0; h < NH; ++h) {
      float l0 = oar[64 + h * 4 + 0];
      float l1 = oar[64 + h * 4 + 1];
      float l2 = oar[64 + h * 4 + 2];
      float l3 = oar[64 + h * 4 + 3];
      float mx = fmaxf(fmaxf(l0, l1), fmaxf(l2, l3));
      float e0 = __expf(l0 - mx), e1 = __expf(l1 - mx);
      float e2 = __expf(l2 - mx), e3 = __expf(l3 - mx);
      float inv = 1.f / (e0 + e1 + e2 + e3);
      float awp[4] = {e0 * inv, e1 * inv, e2 * inv, e3 * inv};
      float fa[8] = {0.f, 0.f, 0.f, 0.f, 0.f, 0.f, 0.f, 0.f};
      const __bf16* vh = v + ((size_t)h * M + (size_t)b * NQ) * 32 + c8;
#pragma unroll
      for (int p = 0; p < NP; ++p) {
        float ox = oar[h * 8 + p * 2 + 0];
        float oy = oar[h * 8 + p * 2 + 1];
        float ix = (float)x + ox;
        float iy = (float)y + oy;
        float x0f = floorf(ix), y0f = floorf(iy);
        float wx1 = ix - x0f, wy1 = iy - y0f;
        int x0 = (int)x0f, y0 = (int)y0f;
        float wgt[4] = {(1.f - wx1) * (1.f - wy1), wx1 * (1.f - wy1),
                        (1.f - wx1) * wy1, wx1 * wy1};
        int xs[4] = {x0, x0 + 1, x0, x0 + 1};
        int ysv[4] = {y0, y0, y0 + 1, y0 + 1};
#pragma unroll
        for (int c = 0; c < 4; ++c) {
          int xi = xs[c], yi = ysv[c];
          bool valid = (xi >= 0) & (xi < W_IMG) & (yi >= 0) & (yi < H_IMG);
          int xc = xi < 0 ? 0 : (xi > W_IMG - 1 ? W_IMG - 1 : xi);
          int yc = yi < 0 ? 0 : (yi > H_IMG - 1 ? H_IMG - 1 : yi);
          float wv = awp[p] * wgt[c] * (valid ? 1.f : 0.f);
          bf16x8 g = *(const bf16x8*)(vh + (size_t)(yc * W_IMG + xc) * 32);
#pragma unroll
          for (int j = 0; j < 8; ++j) fa[j] += wv * (float)g[j];
        }
      }
      bf16x8 o;
#pragma unroll
      for (int j = 0; j < 8; ++j) o[j] = (__bf16)fa[j];
      *(bf16x8*)(&As[qrow * LDSP + h * DH + c8]) = o;
    }
  }
  __syncthreads();  // attn tile ready in As

  // ---- phase 4: out GEMM (wave: 64 rows x 64 cols = 4x4 tiles) ----
  {
    const int wn = wave * 64;
    // issue residual loads EARLY: latency hides under the 128-MFMA k-loop
    float res[4][4][4];
#pragma unroll
    for (int mt = 0; mt < 4; ++mt)
#pragma unroll
      for (int nt = 0; nt < 4; ++nt)
#pragma unroll
        for (int rr = 0; rr < 4; ++rr)
          res[mt][nt][rr] =
              query[(size_t)(gm0 + mt * 16 + q * 4 + rr) * 256 + wn + nt * 16 + r];

    f32x4 acc[4][4];
#pragma unroll
    for (int mt = 0; mt < 4; ++mt)
#pragma unroll
      for (int nt = 0; nt < 4; ++nt) acc[mt][nt] = (f32x4){0.f, 0.f, 0.f, 0.f};

    bf16x8 bnx[4];
#pragma unroll
    for (int nt = 0; nt < 4; ++nt)
      bnx[nt] = *(const bf16x8*)(bto + (size_t)(wn + nt * 16 + r) * 256 + q * 8);
#pragma unroll
    for (int kt = 0; kt < 8; ++kt) {
      const int ko = kt * 32 + q * 8;
      bf16x8 b[4];
#pragma unroll
      for (int nt = 0; nt < 4; ++nt) b[nt] = bnx[nt];
      if (kt < 7) {
#pragma unroll
        for (int nt = 0; nt < 4; ++nt)
          bnx[nt] = *(const bf16x8*)(bto + (size_t)(wn + nt * 16 + r) * 256 + ko + 32);
      }
      bf16x8 a[4];
#pragma unroll
      for (int mt = 0; mt < 4; ++mt)
        a[mt] = *(const bf16x8*)(&As[(mt * 16 + r) * LDSP + ko]);
#pragma unroll
      for (int mt = 0; mt < 4; ++mt)
#pragma unroll
        for (int nt = 0; nt < 4; ++nt)
          acc[mt][nt] =
              __builtin_amdgcn_mfma_f32_16x16x32_bf16(a[mt], b[nt], acc[mt][nt], 0, 0, 0);
    }
#pragma unroll
    for (int mt = 0; mt < 4; ++mt)
#pragma unroll
      for (int nt = 0; nt < 4; ++nt)
#pragma unroll
        for (int rr = 0; rr < 4; ++rr) {
          int row = gm0 + mt * 16 + q * 4 + rr;
          int col = wn + nt * 16 + r;
          out[(size_t)row * 256 + col] =
              acc[mt][nt][rr] + b_out[col] + res[mt][nt][rr];
        }
  }
}

extern "C" void kernel_launch(void* const* d_in, const int* in_sizes, int n_in,
                              void* d_out, int out_size, void* d_ws, size_t ws_size,
                              hipStream_t stream) {
  const float* query  = (const float*)d_in[0];
  const float* value  = (const float*)d_in[1];
  const float* W_off  = (const float*)d_in[2];
  const float* b_off  = (const float*)d_in[3];
  const float* W_attn = (const float*)d_in[4];
  const float* b_attn = (const float*)d_in[5];
  const float* W_val  = (const float*)d_in[6];
  const float* b_val  = (const float*)d_in[7];
  const float* W_out  = (const float*)d_in[8];
  const float* b_out  = (const float*)d_in[9];
  float* out = (float*)d_out;

  char* ws = (char*)d_ws;
  __bf16* btv    = (__bf16*)(ws + 0);          // 128 KB
  __bf16* bto    = (__bf16*)(ws + 131072);     // 128 KB
  __bf16* btoa   = (__bf16*)(ws + 262144);     // 48 KB
  float*  bias96 = (float*)(ws + 311296);      // 384 B
  __bf16* v      = (__bf16*)(ws + 524288);     // 16 MB (bf16, head-planar)

  const int M = in_sizes[0] / CIN;  // 32768 = bs * nq

  prep_weights<<<256, 256, 0, stream>>>(W_val, W_out, W_off, W_attn,
                                        b_off, b_attn, btv, bto, btoa, bias96);
  gemm_v<<<M / 64, 256, 0, stream>>>(value, btv, b_val, v, M);
  oa_sample_out<<<M / 64, 256, 0, stream>>>(query, btoa, bias96, v, bto, b_out, out, M);
}